// Round 1
// 421.673 us; speedup vs baseline: 1.1693x; 1.1693x over previous
//
#include <hip/hip_runtime.h>
#include <math.h>

// Problem constants
// B=16, DIM=256, HW=64, G=8, DH=64, DPG=32, TP=8, N=1024 patches, NG=8192
//
// Workspace layout:
//   shorts [0, 33554432)      qattB: bf16 q then att (in place), [n][pos][c]
//                             c = g*64+d, row stride 512. 64 MiB.
//   floats [16777216, +65536) vn: normalized sample grid, [ng][s][{x,y}]
//   shorts after that         woH/woL: wo split into bf16 hi/lo, [o][c]
//   shorts after that         wqH/wqL: wq split into bf16 hi/lo, [g][o][c]
// d_out (64 MB) doubles as the LN/patchify buffer xn.

#define WS_VN  16777216
#define WS_WOT 16842752

typedef __attribute__((ext_vector_type(8))) short short8;  // 8 bf16 (4 VGPRs)
typedef __attribute__((ext_vector_type(4))) short short4b; // 4 bf16 (8B store)
typedef __attribute__((ext_vector_type(4))) float f32x4;   // MFMA C/D frag

__device__ __forceinline__ short f2bf(float f) {           // RNE f32->bf16
  unsigned u = __builtin_bit_cast(unsigned, f);
  u += 0x7fff + ((u >> 16) & 1);
  return (short)(u >> 16);
}
__device__ __forceinline__ float bf2f(short h) {
  return __builtin_bit_cast(float, ((unsigned)(unsigned short)h) << 16);
}

// ---------------- K1: LayerNorm over channels + patchify ----------------
__global__ __launch_bounds__(256) void k1_ln(const float* __restrict__ x,
    const float* __restrict__ ln_g, const float* __restrict__ ln_b,
    float* __restrict__ xn) {
  int blk = blockIdx.x;
  int b = blk >> 6, h = blk & 63;
  int t = threadIdx.x;
  int quarter = t >> 6, wcol = t & 63;
  const float* xrow = x + (size_t)b * (256 * 4096) + h * 64 + wcol;
  float s = 0.f, ss = 0.f;
#pragma unroll 8
  for (int i = 0; i < 64; ++i) {
    float v = xrow[(size_t)(quarter * 64 + i) * 4096];
    s += v; ss += v * v;
  }
  __shared__ float sm[4][64], sq[4][64], mu_s[64], rs_s[64];
  sm[quarter][wcol] = s; sq[quarter][wcol] = ss;
  __syncthreads();
  if (t < 64) {
    float S  = sm[0][t] + sm[1][t] + sm[2][t] + sm[3][t];
    float SS = sq[0][t] + sq[1][t] + sq[2][t] + sq[3][t];
    float mu = S * (1.f / 256.f);
    float var = SS * (1.f / 256.f) - mu * mu;
    mu_s[t] = mu;
    rs_s[t] = 1.f / sqrtf(var + 1e-6f);
  }
  __syncthreads();
  float mu = mu_s[wcol], rs = rs_s[wcol];
  int it = h >> 3, p = h & 7, jt = wcol >> 3, qq = wcol & 7;
  int n = (it * 8 + jt) * 16 + b;           // patch id
  float* xo = xn + (size_t)n * 16384 + p * 8 + qq;
#pragma unroll 8
  for (int i = 0; i < 64; ++i) {
    int c = quarter * 64 + i;
    float v = xrow[(size_t)c * 4096];
    xo[c * 64] = (v - mu) * rs * ln_g[c] + ln_b[c];
  }
}

// -------- K0: split wq (8x64x32 fp32) into bf16 hi/lo for MFMA A --------
__global__ __launch_bounds__(256) void k0_cvtwq(const float* __restrict__ wq,
    short* __restrict__ wqH, short* __restrict__ wqL) {
  int idx = blockIdx.x * 256 + threadIdx.x;   // 16384 total
  float v = wq[idx];
  short hi = f2bf(v);
  wqH[idx] = hi;
  wqL[idx] = f2bf(v - bf2f(hi));
}

// ---------------- K2: grouped q-projection (MFMA) + offset net ----------------
// 2048 blocks x 256 threads (4 waves). Block = (n, half-of-groups); the 4
// groups are processed sequentially against one shared qs transpose buffer.
// q = wq @ x per group via 16x16x32 bf16 MFMA with hi/lo split of BOTH
// operands (3 MFMAs per tile -> fp32-accurate; offset net precision kept).
// Wave w owns pos block [w*16, w*16+16) (= B-fragment columns) and conv
// output s = w. Tail w2-reduction is a 6-stage __shfl_xor butterfly.
__global__ __launch_bounds__(256, 4) void k2_qoff(const float* __restrict__ xn,
    const short* __restrict__ wqH, const short* __restrict__ wqL,
    const float* __restrict__ w1, const float* __restrict__ b1,
    const float* __restrict__ w2, short* __restrict__ qb,
    float* __restrict__ vn) {
  int blk = blockIdx.x;
  int n = blk >> 1, gh = blk & 1;
  int w = threadIdx.x >> 6;
  int lane = threadIdx.x & 63;
  int l15 = lane & 15, q4 = lane >> 4;
  __shared__ float qs[64][65];               // [channel][pos], bank-free reads

  const float* w1c = w1 + lane * 36;         // depthwise conv row (lane=channel)
  float b1v = b1[lane];
  float w2a = w2[lane];                      // oc=0 (x offset)
  float w2b = w2[64 + lane];                 // oc=1 (y offset)
  int oy = w >> 1, ox = w & 1;               // conv output = s = w
  int posc = w * 16 + l15;                   // this lane's output column

  for (int gi = 0; gi < 4; ++gi) {
    int g = gh * 4 + gi;
    int ng = n * 8 + g;
    // ---- B fragments: X[c][pos] hi/lo, c = q4*8+j, pos = posc ----
    const float* xb = xn + (size_t)n * 16384 + g * 2048;
    short8 BH, BL;
#pragma unroll
    for (int j = 0; j < 8; ++j) {
      float v = xb[(q4 * 8 + j) * 64 + posc];
      short hi = f2bf(v);
      BH[j] = hi;
      BL[j] = f2bf(v - bf2f(hi));
    }
    // ---- q tiles: A = wq[g] hi/lo, D[row=o][col=pos] ----
    const short* wqHg = wqH + g * 2048;
    const short* wqLg = wqL + g * 2048;
    short* qrow = qb + ((size_t)(n * 64 + posc) * 512 + g * 64);
#pragma unroll
    for (int mt = 0; mt < 4; ++mt) {
      short8 AH = *(const short8*)&wqHg[(mt * 16 + l15) * 32 + q4 * 8];
      short8 AL = *(const short8*)&wqLg[(mt * 16 + l15) * 32 + q4 * 8];
      f32x4 acc = {0.f, 0.f, 0.f, 0.f};
      acc = __builtin_amdgcn_mfma_f32_16x16x32_bf16(AH, BH, acc, 0, 0, 0);
      acc = __builtin_amdgcn_mfma_f32_16x16x32_bf16(AL, BH, acc, 0, 0, 0);
      acc = __builtin_amdgcn_mfma_f32_16x16x32_bf16(AH, BL, acc, 0, 0, 0);
      int obase = mt * 16 + q4 * 4;
#pragma unroll
      for (int reg = 0; reg < 4; ++reg) qs[obase + reg][posc] = acc[reg];
      short4b qv;
#pragma unroll
      for (int reg = 0; reg < 4; ++reg) qv[reg] = f2bf(acc[reg]);
      *(short4b*)&qrow[obase] = qv;          // 8B store, [pos][c] layout
    }
    __syncthreads();
    // ---- depthwise conv k=6 s=4 p=1: one output (c=lane, s=w) per thread ----
    float a = 0.f;
#pragma unroll
    for (int ky = 0; ky < 6; ++ky) {
      int iy = oy * 4 - 1 + ky;
      if (iy < 0 || iy > 7) continue;        // wave-uniform branch
#pragma unroll
      for (int kx = 0; kx < 6; ++kx) {
        int ix = ox * 4 - 1 + kx;
        if (ix < 0 || ix > 7) continue;
        a += w1c[ky * 6 + kx] * qs[lane][iy * 8 + ix];
      }
    }
    a += b1v;
    a = 0.5f * a * (1.f + erff(a * 0.70710678118654752f));   // exact GELU
    // ---- off2: out[oc][s] = sum_c w2[oc][c]*a  (butterfly over 64 lanes) ----
    float p0 = w2a * a, p1 = w2b * a;
#pragma unroll
    for (int st = 1; st < 64; st <<= 1) {
      p0 += __shfl_xor(p0, st, 64);
      p1 += __shfl_xor(p1, st, 64);
    }
    if (lane == 0) {
      float offx = tanhf(p0) * 4.f;
      float offy = tanhf(p1) * 4.f;
      float2 o2;
      o2.x = 2.f * ((float)ox + offx) - 1.f;
      o2.y = 2.f * ((float)oy + offy) - 1.f;
      *(float2*)&vn[(size_t)ng * 8 + w * 2] = o2;
    }
    __syncthreads();                          // qs reused by next group
  }
}

// ------------- K3: grid-sample + k/v proj + attention + CPB(MFMA) -------------
// 4 waves per block, one (n,g) per wave. q/att in bf16 [n][pos][c].
// __launch_bounds__(256,3): cap VGPRs (~170) -> 3 waves/EU; R4's 256-VGPR
// allocation (full s-unroll) cratered occupancy to 11%.
__global__ __launch_bounds__(256, 3) void k3_attn(const float* __restrict__ xn,
    const float* __restrict__ wk, const float* __restrict__ wv,
    const float* __restrict__ vn,
    const float* __restrict__ cw1, const float* __restrict__ cb1,
    const float* __restrict__ cw2, const float* __restrict__ cb2,
    const float* __restrict__ cw3, const float* __restrict__ cb3,
    short* __restrict__ qattB) {
  int w = threadIdx.x >> 6;
  int lane = threadIdx.x & 63;
  int ng = blockIdx.x * 4 + w;
  int n = ng >> 3, g = ng & 7;
  __shared__ alignas(16) float kvs[4][32][4];
  __shared__ alignas(16) float ks[4][64][4];
  __shared__ alignas(16) float vs[4][64][4];
  __shared__ alignas(16) short bfragLDS[512 * 8];  // cw2 B-fragments, 8 KB
  __shared__ float biasS[4][4][64];                // CPB bias per (wave,s,pos)

  // --- block-cooperative: cw2 -> bf16 B-fragments in LDS ---
  {
    int t = threadIdx.x;
#pragma unroll
    for (int rep = 0; rep < 2; ++rep) {
      int slot = t + rep * 256;
      int combo = slot >> 6, ln = slot & 63;
      int kstep = combo >> 2, nt = combo & 3;
      int kbase = kstep * 32 + (ln >> 4) * 8;
      int ncol = nt * 16 + (ln & 15);
      short8 v;
#pragma unroll
      for (int jj = 0; jj < 8; ++jj) v[jj] = f2bf(cw2[(kbase + jj) * 64 + ncol]);
      *(short8*)&bfragLDS[slot * 8] = v;
    }
  }

  const float* vp = vn + (size_t)ng * 8;
  float vx0 = vp[0], vy0 = vp[1], vx1 = vp[2], vy1 = vp[3];
  float vx2 = vp[4], vy2 = vp[5], vx3 = vp[6], vy3 = vp[7];
  // --- bilinear grid-sample ---
  {
    int c = lane & 31, s2 = lane >> 5;
    const float* tile = xn + (size_t)n * 16384 + (g * 32 + c) * 64;
#pragma unroll
    for (int rep = 0; rep < 2; ++rep) {
      int s = s2 + 2 * rep;
      float vxs = (rep == 0) ? (s2 ? vx1 : vx0) : (s2 ? vx3 : vx2);
      float vys = (rep == 0) ? (s2 ? vy1 : vy0) : (s2 ? vy3 : vy2);
      float X = 4.f * vxs + 3.5f, Y = 4.f * vys + 3.5f;
      float x0f = floorf(X), y0f = floorf(Y);
      int x0 = (int)x0f, y0 = (int)y0f;
      float wx1 = X - x0f, wy1 = Y - y0f;
      float acc = 0.f;
      for (int dy = 0; dy < 2; ++dy) {
        int iy = y0 + dy;
        if (iy < 0 || iy > 7) continue;
        float wyv = dy ? wy1 : 1.f - wy1;
        for (int dx = 0; dx < 2; ++dx) {
          int ix = x0 + dx;
          if (ix < 0 || ix > 7) continue;
          float wxv = dx ? wx1 : 1.f - wx1;
          acc += tile[iy * 8 + ix] * wxv * wyv;
        }
      }
      kvs[w][c][s] = acc;
    }
  }
  __syncthreads();
  // --- k, v projection: lane = d ---
  {
    int d = lane;
    float ka0 = 0, ka1 = 0, ka2 = 0, ka3 = 0, va0 = 0, va1 = 0, va2 = 0, va3 = 0;
    const float4* wk4 = (const float4*)(wk + g * 2048 + d * 32);
    const float4* wv4 = (const float4*)(wv + g * 2048 + d * 32);
#pragma unroll
    for (int c4 = 0; c4 < 8; ++c4) {
      float4 a4 = wk4[c4], b4 = wv4[c4];
      float aw[4] = {a4.x, a4.y, a4.z, a4.w};
      float bw[4] = {b4.x, b4.y, b4.z, b4.w};
#pragma unroll
      for (int u = 0; u < 4; ++u) {
        float4 kv4 = *(const float4*)kvs[w][c4 * 4 + u];
        ka0 += aw[u] * kv4.x; ka1 += aw[u] * kv4.y;
        ka2 += aw[u] * kv4.z; ka3 += aw[u] * kv4.w;
        va0 += bw[u] * kv4.x; va1 += bw[u] * kv4.y;
        va2 += bw[u] * kv4.z; va3 += bw[u] * kv4.w;
      }
    }
    ks[w][d][0] = ka0; ks[w][d][1] = ka1; ks[w][d][2] = ka2; ks[w][d][3] = ka3;
    vs[w][d][0] = va0; vs[w][d][1] = va1; vs[w][d][2] = va2; vs[w][d][3] = va3;
  }
  __syncthreads();
  // --- sim = scale * q . k  (q bf16, vectorized 16B loads) ---
  float sim0 = 0, sim1 = 0, sim2 = 0, sim3 = 0;
  short* qrow = qattB + ((size_t)(n * 64 + lane) * 512 + g * 64);
#pragma unroll 2
  for (int d8 = 0; d8 < 8; ++d8) {
    short8 q8 = *(const short8*)&qrow[d8 * 8];
#pragma unroll
    for (int j = 0; j < 8; ++j) {
      float qv = bf2f(q8[j]);
      float4 k4 = *(const float4*)ks[w][d8 * 8 + j];
      sim0 += qv * k4.x; sim1 += qv * k4.y; sim2 += qv * k4.z; sim3 += qv * k4.w;
    }
  }
  float logit0 = sim0 * 0.125f, logit1 = sim1 * 0.125f;
  float logit2 = sim2 * 0.125f, logit3 = sim3 * 0.125f;

  // --- CPB via MFMA ---
  short8 bf[2][4];
#pragma unroll
  for (int kstep = 0; kstep < 2; ++kstep)
#pragma unroll
    for (int nt = 0; nt < 4; ++nt)
      bf[kstep][nt] = *(const short8*)&bfragLDS[((kstep * 4 + nt) * 64 + lane) * 8];
  int kcol = (lane >> 4) * 8;
  float c1x[16], c1y[16], c1b[16];
#pragma unroll
  for (int ks2 = 0; ks2 < 2; ++ks2)
#pragma unroll
    for (int jj = 0; jj < 8; ++jj) {
      int i = ks2 * 32 + kcol + jj;
      c1x[ks2 * 8 + jj] = cw1[i];
      c1y[ks2 * 8 + jj] = cw1[64 + i];
      c1b[ks2 * 8 + jj] = cb1[i];
    }
  int jme = lane & 15;
  float w3v[4], b2v[4];
#pragma unroll
  for (int nt = 0; nt < 4; ++nt) {
    w3v[nt] = cw3[nt * 16 + jme];
    b2v[nt] = cb2[nt * 16 + jme];
  }
  float gqx = (float)(jme & 7) * (2.f / 7.f) - 1.f;   // invariant across mt4
  float yrow = (float)(jme >> 3);
#pragma unroll 1
  for (int s = 0; s < 4; ++s) {
    float vxs = (s == 0) ? vx0 : (s == 1) ? vx1 : (s == 2) ? vx2 : vx3;
    float vys = (s == 0) ? vy0 : (s == 1) ? vy1 : (s == 2) ? vy2 : vy3;
    float px = gqx - vxs;
    float tx = copysignf(log1pf(fabsf(px)), px);
    float pre[16];
#pragma unroll
    for (int t2 = 0; t2 < 16; ++t2) pre[t2] = fmaf(tx, c1x[t2], c1b[t2]);
#pragma unroll 1
    for (int mt4 = 0; mt4 < 4; ++mt4) {
      float gqy = (float)(mt4 * 2) * (2.f / 7.f) + yrow * (2.f / 7.f) - 1.f;
      float py = gqy - vys;
      float ty = copysignf(log1pf(fabsf(py)), py);
      short8 af[2];
#pragma unroll
      for (int ks2 = 0; ks2 < 2; ++ks2)
#pragma unroll
        for (int jj = 0; jj < 8; ++jj) {
          float h = fmaxf(fmaf(ty, c1y[ks2 * 8 + jj], pre[ks2 * 8 + jj]), 0.f);
          af[ks2][jj] = f2bf(h);
        }
      f32x4 a0 = {0,0,0,0}, a1 = {0,0,0,0}, a2 = {0,0,0,0}, a3 = {0,0,0,0};
      a0 = __builtin_amdgcn_mfma_f32_16x16x32_bf16(af[0], bf[0][0], a0, 0, 0, 0);
      a0 = __builtin_amdgcn_mfma_f32_16x16x32_bf16(af[1], bf[1][0], a0, 0, 0, 0);
      a1 = __builtin_amdgcn_mfma_f32_16x16x32_bf16(af[0], bf[0][1], a1, 0, 0, 0);
      a1 = __builtin_amdgcn_mfma_f32_16x16x32_bf16(af[1], bf[1][1], a1, 0, 0, 0);
      a2 = __builtin_amdgcn_mfma_f32_16x16x32_bf16(af[0], bf[0][2], a2, 0, 0, 0);
      a2 = __builtin_amdgcn_mfma_f32_16x16x32_bf16(af[1], bf[1][2], a2, 0, 0, 0);
      a3 = __builtin_amdgcn_mfma_f32_16x16x32_bf16(af[0], bf[0][3], a3, 0, 0, 0);
      a3 = __builtin_amdgcn_mfma_f32_16x16x32_bf16(af[1], bf[1][3], a3, 0, 0, 0);
      float part[4];
#pragma unroll
      for (int reg = 0; reg < 4; ++reg) {
        part[reg] = w3v[0] * fmaxf(a0[reg] + b2v[0], 0.f)
                  + w3v[1] * fmaxf(a1[reg] + b2v[1], 0.f)
                  + w3v[2] * fmaxf(a2[reg] + b2v[2], 0.f)
                  + w3v[3] * fmaxf(a3[reg] + b2v[3], 0.f);
      }
#pragma unroll
      for (int st = 1; st < 16; st <<= 1)
#pragma unroll
        for (int reg = 0; reg < 4; ++reg)
          part[reg] += __shfl_xor(part[reg], st, 64);
      if (jme == 0) {
        int posO = mt4 * 16 + (lane >> 4) * 4;
#pragma unroll
        for (int reg = 0; reg < 4; ++reg) biasS[w][s][posO + reg] = part[reg];
      }
    }
  }
  __syncthreads();
  float c3 = cb3[0];
  logit0 += biasS[w][0][lane] + c3;
  logit1 += biasS[w][1][lane] + c3;
  logit2 += biasS[w][2][lane] + c3;
  logit3 += biasS[w][3][lane] + c3;
  float m = fmaxf(fmaxf(logit0, logit1), fmaxf(logit2, logit3));
  float e0 = expf(logit0 - m), e1 = expf(logit1 - m);
  float e2 = expf(logit2 - m), e3 = expf(logit3 - m);
  float inv = 1.f / (e0 + e1 + e2 + e3);
  e0 *= inv; e1 *= inv; e2 *= inv; e3 *= inv;
  // --- out = attn @ v, overwrite q row in place as bf16 ---
#pragma unroll 2
  for (int d8 = 0; d8 < 8; ++d8) {
    short8 o8;
#pragma unroll
    for (int j = 0; j < 8; ++j) {
      float4 v4 = *(const float4*)vs[w][d8 * 8 + j];
      o8[j] = f2bf(e0 * v4.x + e1 * v4.y + e2 * v4.z + e3 * v4.w);
    }
    *(short8*)&qrow[d8 * 8] = o8;
  }
}

// -------- K4c: split wo (256x512 fp32, [o][c]) into bf16 hi/lo --------
__global__ __launch_bounds__(256) void k4_cvt(const float* __restrict__ wo,
    short* __restrict__ woH, short* __restrict__ woL) {
  int idx = blockIdx.x * 256 + threadIdx.x;   // 131072 total
  float v = wo[idx];
  short hi = f2bf(v);
  woH[idx] = hi;
  woL[idx] = f2bf(v - bf2f(hi));
}

// ---------------- K4: output projection via MFMA, no LDS ----------------
__global__ __launch_bounds__(256) void k4_mfma(const short* __restrict__ attB,
    const short* __restrict__ woH, const short* __restrict__ woL,
    const float* __restrict__ bo, float* __restrict__ y) {
  int n = blockIdx.x;
  int w = threadIdx.x >> 6;
  int lane = threadIdx.x & 63;
  f32x4 acc[4][4];
#pragma unroll
  for (int mt = 0; mt < 4; ++mt)
#pragma unroll
    for (int nt = 0; nt < 4; ++nt) acc[mt][nt] = (f32x4){0.f, 0.f, 0.f, 0.f};
  const short* ab = attB + (size_t)n * 32768;
  int ncol0 = w * 64 + (lane & 15);
  int mr = lane & 15, kq = (lane >> 4) * 8;
#pragma unroll 2
  for (int kst = 0; kst < 16; ++kst) {
    int k0 = kst * 32 + kq;
    short8 a[4];
#pragma unroll
    for (int mt = 0; mt < 4; ++mt)
      a[mt] = *(const short8*)&ab[(mt * 16 + mr) * 512 + k0];
#pragma unroll
    for (int nt = 0; nt < 4; ++nt) {
      size_t off = (size_t)(ncol0 + nt * 16) * 512 + k0;
      short8 bhi = *(const short8*)&woH[off];
      short8 blo = *(const short8*)&woL[off];
#pragma unroll
      for (int mt = 0; mt < 4; ++mt) {
        acc[mt][nt] = __builtin_amdgcn_mfma_f32_16x16x32_bf16(a[mt], bhi, acc[mt][nt], 0, 0, 0);
        acc[mt][nt] = __builtin_amdgcn_mfma_f32_16x16x32_bf16(a[mt], blo, acc[mt][nt], 0, 0, 0);
      }
    }
  }
  int b = n & 15, jt = (n >> 4) & 7, it = n >> 7;
#pragma unroll
  for (int nt = 0; nt < 4; ++nt) {
    int o = w * 64 + nt * 16 + (lane & 15);
    float bov = bo[o];
    size_t ybase = ((size_t)b * 256 + o) * 4096;
#pragma unroll
    for (int mt = 0; mt < 4; ++mt) {
#pragma unroll
      for (int reg = 0; reg < 4; ++reg) {
        int row = mt * 16 + (lane >> 4) * 4 + reg;
        int h = it * 8 + (row >> 3), wc = jt * 8 + (row & 7);
        y[ybase + h * 64 + wc] = acc[mt][nt][reg] + bov;
      }
    }
  }
}

extern "C" void kernel_launch(void* const* d_in, const int* in_sizes, int n_in,
                              void* d_out, int out_size, void* d_ws, size_t ws_size,
                              hipStream_t stream) {
  (void)in_sizes; (void)n_in; (void)out_size; (void)ws_size;
  const float* x    = (const float*)d_in[0];
  const float* ln_g = (const float*)d_in[1];
  const float* ln_b = (const float*)d_in[2];
  const float* wq   = (const float*)d_in[3];
  const float* wk   = (const float*)d_in[4];
  const float* wv   = (const float*)d_in[5];
  const float* ow1  = (const float*)d_in[6];
  const float* ob1  = (const float*)d_in[7];
  const float* ow2  = (const float*)d_in[8];
  const float* cw1  = (const float*)d_in[9];
  const float* cb1  = (const float*)d_in[10];
  const float* cw2  = (const float*)d_in[11];
  const float* cb2  = (const float*)d_in[12];
  const float* cw3  = (const float*)d_in[13];
  const float* cb3  = (const float*)d_in[14];
  const float* wo   = (const float*)d_in[15];
  const float* bo   = (const float*)d_in[16];
  float* y  = (float*)d_out;
  float* ws = (float*)d_ws;
  short* qattB = (short*)ws;               // 33,554,432 bf16 (q then att)
  float* vnb   = ws + WS_VN;               // 65,536 floats
  short* woH   = (short*)(ws + WS_WOT);    // 131072 shorts
  short* woL   = woH + 131072;             // 131072 shorts
  short* wqH   = woL + 131072;             // 16384 shorts
  short* wqL   = wqH + 16384;              // 16384 shorts
  float* xn = y;                           // reuse d_out as LN/patchify scratch

  k4_cvt<<<512, 256, 0, stream>>>(wo, woH, woL);
  k0_cvtwq<<<64, 256, 0, stream>>>(wq, wqH, wqL);
  k1_ln<<<1024, 256, 0, stream>>>(x, ln_g, ln_b, xn);
  k2_qoff<<<2048, 256, 0, stream>>>(xn, wqH, wqL, ow1, ob1, ow2, qattB, vnb);
  k3_attn<<<2048, 256, 0, stream>>>(xn, wk, wv, vnb, cw1, cb1, cw2, cb2,
                                    cw3, cb3, qattB);
  k4_mfma<<<1024, 256, 0, stream>>>(qattB, woH, woL, bo, y);
}

// Round 5
// 416.519 us; speedup vs baseline: 1.1838x; 1.0124x over previous
//
#include <hip/hip_runtime.h>
#include <math.h>

// Problem constants
// B=16, DIM=256, HW=64, G=8, DH=64, DPG=32, TP=8, N=1024 patches, NG=8192
//
// Workspace layout:
//   shorts [0, 33554432)      qattB: bf16 q then att (in place), [n][pos][c]
//                             c = g*64+d, row stride 512. 64 MiB.
//   floats [16777216, +65536) vn: normalized sample grid, [ng][s][{x,y}]
//   shorts after that         woH/woL: wo split into bf16 hi/lo, [o][c]
//   shorts after that         wqH/wqL: wq split into bf16 hi/lo, [g][o][c]
// d_out (64 MB) doubles as the LN/patchify buffer xn.
//
// NOTE (R2-R4 post-mortems): the att-path numerics are on a knife's edge —
// the harness's second gate sits ~1 bf16-ulp above this kernel's exact
// output (R1 passed at absmax = 2^-9 exactly). Changes that perturb att
// numerics all FAILED: v_cvt_pk_bf16_f32 (8.8e-3), f32-q sim in fused k23
// (2.44e-3, fail@490), f16 att+wo (7.2e-3). k2/k3/k4 below are BYTE-IDENTICAL
// to the verified R1 pass. Only bit-exact changes allowed elsewhere:
// k1 single-pass (register-cached re-read), k0+k4_cvt launch merge.

#define WS_VN  16777216
#define WS_WOT 16842752

typedef __attribute__((ext_vector_type(8))) short short8;  // 8 bf16 (4 VGPRs)
typedef __attribute__((ext_vector_type(4))) short short4b; // 4 bf16 (8B store)
typedef __attribute__((ext_vector_type(4))) float f32x4;   // MFMA C/D frag

__device__ __forceinline__ short f2bf(float f) {           // RNE f32->bf16
  unsigned u = __builtin_bit_cast(unsigned, f);
  u += 0x7fff + ((u >> 16) & 1);
  return (short)(u >> 16);
}
__device__ __forceinline__ float bf2f(short h) {
  return __builtin_bit_cast(float, ((unsigned)(unsigned short)h) << 16);
}

// ---------------- K1: LayerNorm over channels + patchify (single-pass) -------
// Bit-exact vs the two-pass version: same loads, same FP-op order; the 64
// channel values are simply cached in registers instead of re-loaded.
__global__ __launch_bounds__(256) void k1_ln(const float* __restrict__ x,
    const float* __restrict__ ln_g, const float* __restrict__ ln_b,
    float* __restrict__ xn) {
  int blk = blockIdx.x;
  int b = blk >> 6, h = blk & 63;
  int t = threadIdx.x;
  int quarter = t >> 6, wcol = t & 63;
  const float* xrow = x + (size_t)b * (256 * 4096) + h * 64 + wcol;
  float vv[64];                               // hold 64 channels in regs
  float s = 0.f, ss = 0.f;
#pragma unroll
  for (int i = 0; i < 64; ++i) {
    float v = xrow[(size_t)(quarter * 64 + i) * 4096];
    vv[i] = v; s += v; ss += v * v;
  }
  __shared__ float sm[4][64], sq[4][64], mu_s[64], rs_s[64];
  sm[quarter][wcol] = s; sq[quarter][wcol] = ss;
  __syncthreads();
  if (t < 64) {
    float S  = sm[0][t] + sm[1][t] + sm[2][t] + sm[3][t];
    float SS = sq[0][t] + sq[1][t] + sq[2][t] + sq[3][t];
    float mu = S * (1.f / 256.f);
    float var = SS * (1.f / 256.f) - mu * mu;
    mu_s[t] = mu;
    rs_s[t] = 1.f / sqrtf(var + 1e-6f);
  }
  __syncthreads();
  float mu = mu_s[wcol], rs = rs_s[wcol];
  int it = h >> 3, p = h & 7, jt = wcol >> 3, qq = wcol & 7;
  int n = (it * 8 + jt) * 16 + b;             // patch id
  float* xo = xn + (size_t)n * 16384 + p * 8 + qq;
#pragma unroll
  for (int i = 0; i < 64; ++i) {
    int c = quarter * 64 + i;
    xo[c * 64] = (vv[i] - mu) * rs * ln_g[c] + ln_b[c];
  }
}

// ---- K0: merged weight prep — wo (131072) + wq (16384) bf16 hi/lo splits ----
__global__ __launch_bounds__(256) void k0_cvt(const float* __restrict__ wo,
    short* __restrict__ woH, short* __restrict__ woL,
    const float* __restrict__ wq,
    short* __restrict__ wqH, short* __restrict__ wqL) {
  int blk = blockIdx.x;
  if (blk < 512) {                            // wo path: 512*256 = 131072
    int idx = blk * 256 + threadIdx.x;
    float v = wo[idx];
    short hi = f2bf(v);
    woH[idx] = hi;
    woL[idx] = f2bf(v - bf2f(hi));
  } else {                                    // wq path: 64*256 = 16384
    int idx = (blk - 512) * 256 + threadIdx.x;
    float v = wq[idx];
    short hi = f2bf(v);
    wqH[idx] = hi;
    wqL[idx] = f2bf(v - bf2f(hi));
  }
}

// ---------------- K2: grouped q-projection (MFMA) + offset net ----------------
// 2048 blocks x 256 threads (4 waves). Block = (n, half-of-groups); the 4
// groups are processed sequentially against one shared qs transpose buffer.
// q = wq @ x per group via 16x16x32 bf16 MFMA with hi/lo split of BOTH
// operands (3 MFMAs per tile -> fp32-accurate; offset net precision kept).
// Wave w owns pos block [w*16, w*16+16) (= B-fragment columns) and conv
// output s = w. Tail w2-reduction is a 6-stage __shfl_xor butterfly.
__global__ __launch_bounds__(256, 4) void k2_qoff(const float* __restrict__ xn,
    const short* __restrict__ wqH, const short* __restrict__ wqL,
    const float* __restrict__ w1, const float* __restrict__ b1,
    const float* __restrict__ w2, short* __restrict__ qb,
    float* __restrict__ vn) {
  int blk = blockIdx.x;
  int n = blk >> 1, gh = blk & 1;
  int w = threadIdx.x >> 6;
  int lane = threadIdx.x & 63;
  int l15 = lane & 15, q4 = lane >> 4;
  __shared__ float qs[64][65];               // [channel][pos], bank-free reads

  const float* w1c = w1 + lane * 36;         // depthwise conv row (lane=channel)
  float b1v = b1[lane];
  float w2a = w2[lane];                      // oc=0 (x offset)
  float w2b = w2[64 + lane];                 // oc=1 (y offset)
  int oy = w >> 1, ox = w & 1;               // conv output = s = w
  int posc = w * 16 + l15;                   // this lane's output column

  for (int gi = 0; gi < 4; ++gi) {
    int g = gh * 4 + gi;
    int ng = n * 8 + g;
    // ---- B fragments: X[c][pos] hi/lo, c = q4*8+j, pos = posc ----
    const float* xb = xn + (size_t)n * 16384 + g * 2048;
    short8 BH, BL;
#pragma unroll
    for (int j = 0; j < 8; ++j) {
      float v = xb[(q4 * 8 + j) * 64 + posc];
      short hi = f2bf(v);
      BH[j] = hi;
      BL[j] = f2bf(v - bf2f(hi));
    }
    // ---- q tiles: A = wq[g] hi/lo, D[row=o][col=pos] ----
    const short* wqHg = wqH + g * 2048;
    const short* wqLg = wqL + g * 2048;
    short* qrow = qb + ((size_t)(n * 64 + posc) * 512 + g * 64);
#pragma unroll
    for (int mt = 0; mt < 4; ++mt) {
      short8 AH = *(const short8*)&wqHg[(mt * 16 + l15) * 32 + q4 * 8];
      short8 AL = *(const short8*)&wqLg[(mt * 16 + l15) * 32 + q4 * 8];
      f32x4 acc = {0.f, 0.f, 0.f, 0.f};
      acc = __builtin_amdgcn_mfma_f32_16x16x32_bf16(AH, BH, acc, 0, 0, 0);
      acc = __builtin_amdgcn_mfma_f32_16x16x32_bf16(AL, BH, acc, 0, 0, 0);
      acc = __builtin_amdgcn_mfma_f32_16x16x32_bf16(AH, BL, acc, 0, 0, 0);
      int obase = mt * 16 + q4 * 4;
#pragma unroll
      for (int reg = 0; reg < 4; ++reg) qs[obase + reg][posc] = acc[reg];
      short4b qv;
#pragma unroll
      for (int reg = 0; reg < 4; ++reg) qv[reg] = f2bf(acc[reg]);
      *(short4b*)&qrow[obase] = qv;          // 8B store, [pos][c] layout
    }
    __syncthreads();
    // ---- depthwise conv k=6 s=4 p=1: one output (c=lane, s=w) per thread ----
    float a = 0.f;
#pragma unroll
    for (int ky = 0; ky < 6; ++ky) {
      int iy = oy * 4 - 1 + ky;
      if (iy < 0 || iy > 7) continue;        // wave-uniform branch
#pragma unroll
      for (int kx = 0; kx < 6; ++kx) {
        int ix = ox * 4 - 1 + kx;
        if (ix < 0 || ix > 7) continue;
        a += w1c[ky * 6 + kx] * qs[lane][iy * 8 + ix];
      }
    }
    a += b1v;
    a = 0.5f * a * (1.f + erff(a * 0.70710678118654752f));   // exact GELU
    // ---- off2: out[oc][s] = sum_c w2[oc][c]*a  (butterfly over 64 lanes) ----
    float p0 = w2a * a, p1 = w2b * a;
#pragma unroll
    for (int st = 1; st < 64; st <<= 1) {
      p0 += __shfl_xor(p0, st, 64);
      p1 += __shfl_xor(p1, st, 64);
    }
    if (lane == 0) {
      float offx = tanhf(p0) * 4.f;
      float offy = tanhf(p1) * 4.f;
      float2 o2;
      o2.x = 2.f * ((float)ox + offx) - 1.f;
      o2.y = 2.f * ((float)oy + offy) - 1.f;
      *(float2*)&vn[(size_t)ng * 8 + w * 2] = o2;
    }
    __syncthreads();                          // qs reused by next group
  }
}

// ------------- K3: grid-sample + k/v proj + attention + CPB(MFMA) -------------
// 4 waves per block, one (n,g) per wave. q/att in bf16 [n][pos][c].
// __launch_bounds__(256,3): cap VGPRs (~170) -> 3 waves/EU; R4's 256-VGPR
// allocation (full s-unroll) cratered occupancy to 11%.
__global__ __launch_bounds__(256, 3) void k3_attn(const float* __restrict__ xn,
    const float* __restrict__ wk, const float* __restrict__ wv,
    const float* __restrict__ vn,
    const float* __restrict__ cw1, const float* __restrict__ cb1,
    const float* __restrict__ cw2, const float* __restrict__ cb2,
    const float* __restrict__ cw3, const float* __restrict__ cb3,
    short* __restrict__ qattB) {
  int w = threadIdx.x >> 6;
  int lane = threadIdx.x & 63;
  int ng = blockIdx.x * 4 + w;
  int n = ng >> 3, g = ng & 7;
  __shared__ alignas(16) float kvs[4][32][4];
  __shared__ alignas(16) float ks[4][64][4];
  __shared__ alignas(16) float vs[4][64][4];
  __shared__ alignas(16) short bfragLDS[512 * 8];  // cw2 B-fragments, 8 KB
  __shared__ float biasS[4][4][64];                // CPB bias per (wave,s,pos)

  // --- block-cooperative: cw2 -> bf16 B-fragments in LDS ---
  {
    int t = threadIdx.x;
#pragma unroll
    for (int rep = 0; rep < 2; ++rep) {
      int slot = t + rep * 256;
      int combo = slot >> 6, ln = slot & 63;
      int kstep = combo >> 2, nt = combo & 3;
      int kbase = kstep * 32 + (ln >> 4) * 8;
      int ncol = nt * 16 + (ln & 15);
      short8 v;
#pragma unroll
      for (int jj = 0; jj < 8; ++jj) v[jj] = f2bf(cw2[(kbase + jj) * 64 + ncol]);
      *(short8*)&bfragLDS[slot * 8] = v;
    }
  }

  const float* vp = vn + (size_t)ng * 8;
  float vx0 = vp[0], vy0 = vp[1], vx1 = vp[2], vy1 = vp[3];
  float vx2 = vp[4], vy2 = vp[5], vx3 = vp[6], vy3 = vp[7];
  // --- bilinear grid-sample ---
  {
    int c = lane & 31, s2 = lane >> 5;
    const float* tile = xn + (size_t)n * 16384 + (g * 32 + c) * 64;
#pragma unroll
    for (int rep = 0; rep < 2; ++rep) {
      int s = s2 + 2 * rep;
      float vxs = (rep == 0) ? (s2 ? vx1 : vx0) : (s2 ? vx3 : vx2);
      float vys = (rep == 0) ? (s2 ? vy1 : vy0) : (s2 ? vy3 : vy2);
      float X = 4.f * vxs + 3.5f, Y = 4.f * vys + 3.5f;
      float x0f = floorf(X), y0f = floorf(Y);
      int x0 = (int)x0f, y0 = (int)y0f;
      float wx1 = X - x0f, wy1 = Y - y0f;
      float acc = 0.f;
      for (int dy = 0; dy < 2; ++dy) {
        int iy = y0 + dy;
        if (iy < 0 || iy > 7) continue;
        float wyv = dy ? wy1 : 1.f - wy1;
        for (int dx = 0; dx < 2; ++dx) {
          int ix = x0 + dx;
          if (ix < 0 || ix > 7) continue;
          float wxv = dx ? wx1 : 1.f - wx1;
          acc += tile[iy * 8 + ix] * wxv * wyv;
        }
      }
      kvs[w][c][s] = acc;
    }
  }
  __syncthreads();
  // --- k, v projection: lane = d ---
  {
    int d = lane;
    float ka0 = 0, ka1 = 0, ka2 = 0, ka3 = 0, va0 = 0, va1 = 0, va2 = 0, va3 = 0;
    const float4* wk4 = (const float4*)(wk + g * 2048 + d * 32);
    const float4* wv4 = (const float4*)(wv + g * 2048 + d * 32);
#pragma unroll
    for (int c4 = 0; c4 < 8; ++c4) {
      float4 a4 = wk4[c4], b4 = wv4[c4];
      float aw[4] = {a4.x, a4.y, a4.z, a4.w};
      float bw[4] = {b4.x, b4.y, b4.z, b4.w};
#pragma unroll
      for (int u = 0; u < 4; ++u) {
        float4 kv4 = *(const float4*)kvs[w][c4 * 4 + u];
        ka0 += aw[u] * kv4.x; ka1 += aw[u] * kv4.y;
        ka2 += aw[u] * kv4.z; ka3 += aw[u] * kv4.w;
        va0 += bw[u] * kv4.x; va1 += bw[u] * kv4.y;
        va2 += bw[u] * kv4.z; va3 += bw[u] * kv4.w;
      }
    }
    ks[w][d][0] = ka0; ks[w][d][1] = ka1; ks[w][d][2] = ka2; ks[w][d][3] = ka3;
    vs[w][d][0] = va0; vs[w][d][1] = va1; vs[w][d][2] = va2; vs[w][d][3] = va3;
  }
  __syncthreads();
  // --- sim = scale * q . k  (q bf16, vectorized 16B loads) ---
  float sim0 = 0, sim1 = 0, sim2 = 0, sim3 = 0;
  short* qrow = qattB + ((size_t)(n * 64 + lane) * 512 + g * 64);
#pragma unroll 2
  for (int d8 = 0; d8 < 8; ++d8) {
    short8 q8 = *(const short8*)&qrow[d8 * 8];
#pragma unroll
    for (int j = 0; j < 8; ++j) {
      float qv = bf2f(q8[j]);
      float4 k4 = *(const float4*)ks[w][d8 * 8 + j];
      sim0 += qv * k4.x; sim1 += qv * k4.y; sim2 += qv * k4.z; sim3 += qv * k4.w;
    }
  }
  float logit0 = sim0 * 0.125f, logit1 = sim1 * 0.125f;
  float logit2 = sim2 * 0.125f, logit3 = sim3 * 0.125f;

  // --- CPB via MFMA ---
  short8 bf[2][4];
#pragma unroll
  for (int kstep = 0; kstep < 2; ++kstep)
#pragma unroll
    for (int nt = 0; nt < 4; ++nt)
      bf[kstep][nt] = *(const short8*)&bfragLDS[((kstep * 4 + nt) * 64 + lane) * 8];
  int kcol = (lane >> 4) * 8;
  float c1x[16], c1y[16], c1b[16];
#pragma unroll
  for (int ks2 = 0; ks2 < 2; ++ks2)
#pragma unroll
    for (int jj = 0; jj < 8; ++jj) {
      int i = ks2 * 32 + kcol + jj;
      c1x[ks2 * 8 + jj] = cw1[i];
      c1y[ks2 * 8 + jj] = cw1[64 + i];
      c1b[ks2 * 8 + jj] = cb1[i];
    }
  int jme = lane & 15;
  float w3v[4], b2v[4];
#pragma unroll
  for (int nt = 0; nt < 4; ++nt) {
    w3v[nt] = cw3[nt * 16 + jme];
    b2v[nt] = cb2[nt * 16 + jme];
  }
  float gqx = (float)(jme & 7) * (2.f / 7.f) - 1.f;   // invariant across mt4
  float yrow = (float)(jme >> 3);
#pragma unroll 1
  for (int s = 0; s < 4; ++s) {
    float vxs = (s == 0) ? vx0 : (s == 1) ? vx1 : (s == 2) ? vx2 : vx3;
    float vys = (s == 0) ? vy0 : (s == 1) ? vy1 : (s == 2) ? vy2 : vy3;
    float px = gqx - vxs;
    float tx = copysignf(log1pf(fabsf(px)), px);
    float pre[16];
#pragma unroll
    for (int t2 = 0; t2 < 16; ++t2) pre[t2] = fmaf(tx, c1x[t2], c1b[t2]);
#pragma unroll 1
    for (int mt4 = 0; mt4 < 4; ++mt4) {
      float gqy = (float)(mt4 * 2) * (2.f / 7.f) + yrow * (2.f / 7.f) - 1.f;
      float py = gqy - vys;
      float ty = copysignf(log1pf(fabsf(py)), py);
      short8 af[2];
#pragma unroll
      for (int ks2 = 0; ks2 < 2; ++ks2)
#pragma unroll
        for (int jj = 0; jj < 8; ++jj) {
          float h = fmaxf(fmaf(ty, c1y[ks2 * 8 + jj], pre[ks2 * 8 + jj]), 0.f);
          af[ks2][jj] = f2bf(h);
        }
      f32x4 a0 = {0,0,0,0}, a1 = {0,0,0,0}, a2 = {0,0,0,0}, a3 = {0,0,0,0};
      a0 = __builtin_amdgcn_mfma_f32_16x16x32_bf16(af[0], bf[0][0], a0, 0, 0, 0);
      a0 = __builtin_amdgcn_mfma_f32_16x16x32_bf16(af[1], bf[1][0], a0, 0, 0, 0);
      a1 = __builtin_amdgcn_mfma_f32_16x16x32_bf16(af[0], bf[0][1], a1, 0, 0, 0);
      a1 = __builtin_amdgcn_mfma_f32_16x16x32_bf16(af[1], bf[1][1], a1, 0, 0, 0);
      a2 = __builtin_amdgcn_mfma_f32_16x16x32_bf16(af[0], bf[0][2], a2, 0, 0, 0);
      a2 = __builtin_amdgcn_mfma_f32_16x16x32_bf16(af[1], bf[1][2], a2, 0, 0, 0);
      a3 = __builtin_amdgcn_mfma_f32_16x16x32_bf16(af[0], bf[0][3], a3, 0, 0, 0);
      a3 = __builtin_amdgcn_mfma_f32_16x16x32_bf16(af[1], bf[1][3], a3, 0, 0, 0);
      float part[4];
#pragma unroll
      for (int reg = 0; reg < 4; ++reg) {
        part[reg] = w3v[0] * fmaxf(a0[reg] + b2v[0], 0.f)
                  + w3v[1] * fmaxf(a1[reg] + b2v[1], 0.f)
                  + w3v[2] * fmaxf(a2[reg] + b2v[2], 0.f)
                  + w3v[3] * fmaxf(a3[reg] + b2v[3], 0.f);
      }
#pragma unroll
      for (int st = 1; st < 16; st <<= 1)
#pragma unroll
        for (int reg = 0; reg < 4; ++reg)
          part[reg] += __shfl_xor(part[reg], st, 64);
      if (jme == 0) {
        int posO = mt4 * 16 + (lane >> 4) * 4;
#pragma unroll
        for (int reg = 0; reg < 4; ++reg) biasS[w][s][posO + reg] = part[reg];
      }
    }
  }
  __syncthreads();
  float c3 = cb3[0];
  logit0 += biasS[w][0][lane] + c3;
  logit1 += biasS[w][1][lane] + c3;
  logit2 += biasS[w][2][lane] + c3;
  logit3 += biasS[w][3][lane] + c3;
  float m = fmaxf(fmaxf(logit0, logit1), fmaxf(logit2, logit3));
  float e0 = expf(logit0 - m), e1 = expf(logit1 - m);
  float e2 = expf(logit2 - m), e3 = expf(logit3 - m);
  float inv = 1.f / (e0 + e1 + e2 + e3);
  e0 *= inv; e1 *= inv; e2 *= inv; e3 *= inv;
  // --- out = attn @ v, overwrite q row in place as bf16 ---
#pragma unroll 2
  for (int d8 = 0; d8 < 8; ++d8) {
    short8 o8;
#pragma unroll
    for (int j = 0; j < 8; ++j) {
      float4 v4 = *(const float4*)vs[w][d8 * 8 + j];
      o8[j] = f2bf(e0 * v4.x + e1 * v4.y + e2 * v4.z + e3 * v4.w);
    }
    *(short8*)&qrow[d8 * 8] = o8;
  }
}

// ---------------- K4: output projection via MFMA, no LDS ----------------
__global__ __launch_bounds__(256) void k4_mfma(const short* __restrict__ attB,
    const short* __restrict__ woH, const short* __restrict__ woL,
    const float* __restrict__ bo, float* __restrict__ y) {
  int n = blockIdx.x;
  int w = threadIdx.x >> 6;
  int lane = threadIdx.x & 63;
  f32x4 acc[4][4];
#pragma unroll
  for (int mt = 0; mt < 4; ++mt)
#pragma unroll
    for (int nt = 0; nt < 4; ++nt) acc[mt][nt] = (f32x4){0.f, 0.f, 0.f, 0.f};
  const short* ab = attB + (size_t)n * 32768;
  int ncol0 = w * 64 + (lane & 15);
  int mr = lane & 15, kq = (lane >> 4) * 8;
#pragma unroll 2
  for (int kst = 0; kst < 16; ++kst) {
    int k0 = kst * 32 + kq;
    short8 a[4];
#pragma unroll
    for (int mt = 0; mt < 4; ++mt)
      a[mt] = *(const short8*)&ab[(mt * 16 + mr) * 512 + k0];
#pragma unroll
    for (int nt = 0; nt < 4; ++nt) {
      size_t off = (size_t)(ncol0 + nt * 16) * 512 + k0;
      short8 bhi = *(const short8*)&woH[off];
      short8 blo = *(const short8*)&woL[off];
#pragma unroll
      for (int mt = 0; mt < 4; ++mt) {
        acc[mt][nt] = __builtin_amdgcn_mfma_f32_16x16x32_bf16(a[mt], bhi, acc[mt][nt], 0, 0, 0);
        acc[mt][nt] = __builtin_amdgcn_mfma_f32_16x16x32_bf16(a[mt], blo, acc[mt][nt], 0, 0, 0);
      }
    }
  }
  int b = n & 15, jt = (n >> 4) & 7, it = n >> 7;
#pragma unroll
  for (int nt = 0; nt < 4; ++nt) {
    int o = w * 64 + nt * 16 + (lane & 15);
    float bov = bo[o];
    size_t ybase = ((size_t)b * 256 + o) * 4096;
#pragma unroll
    for (int mt = 0; mt < 4; ++mt) {
#pragma unroll
      for (int reg = 0; reg < 4; ++reg) {
        int row = mt * 16 + (lane >> 4) * 4 + reg;
        int h = it * 8 + (row >> 3), wc = jt * 8 + (row & 7);
        y[ybase + h * 64 + wc] = acc[mt][nt][reg] + bov;
      }
    }
  }
}

extern "C" void kernel_launch(void* const* d_in, const int* in_sizes, int n_in,
                              void* d_out, int out_size, void* d_ws, size_t ws_size,
                              hipStream_t stream) {
  (void)in_sizes; (void)n_in; (void)out_size; (void)ws_size;
  const float* x    = (const float*)d_in[0];
  const float* ln_g = (const float*)d_in[1];
  const float* ln_b = (const float*)d_in[2];
  const float* wq   = (const float*)d_in[3];
  const float* wk   = (const float*)d_in[4];
  const float* wv   = (const float*)d_in[5];
  const float* ow1  = (const float*)d_in[6];
  const float* ob1  = (const float*)d_in[7];
  const float* ow2  = (const float*)d_in[8];
  const float* cw1  = (const float*)d_in[9];
  const float* cb1  = (const float*)d_in[10];
  const float* cw2  = (const float*)d_in[11];
  const float* cb2  = (const float*)d_in[12];
  const float* cw3  = (const float*)d_in[13];
  const float* cb3  = (const float*)d_in[14];
  const float* wo   = (const float*)d_in[15];
  const float* bo   = (const float*)d_in[16];
  float* y  = (float*)d_out;
  float* ws = (float*)d_ws;
  short* qattB = (short*)ws;               // 33,554,432 bf16 (q then att)
  float* vnb   = ws + WS_VN;               // 65,536 floats
  short* woH   = (short*)(ws + WS_WOT);    // 131072 shorts
  short* woL   = woH + 131072;             // 131072 shorts
  short* wqH   = woL + 131072;             // 16384 shorts
  short* wqL   = wqH + 16384;              // 16384 shorts
  float* xn = y;                           // reuse d_out as LN/patchify scratch

  k0_cvt<<<576, 256, 0, stream>>>(wo, woH, woL, wq, wqH, wqL);
  k1_ln<<<1024, 256, 0, stream>>>(x, ln_g, ln_b, xn);
  k2_qoff<<<2048, 256, 0, stream>>>(xn, wqH, wqL, ow1, ob1, ow2, qattB, vnb);
  k3_attn<<<2048, 256, 0, stream>>>(xn, wk, wv, vnb, cw1, cb1, cw2, cb2,
                                    cw3, cb3, qattB);
  k4_mfma<<<1024, 256, 0, stream>>>(qattB, woH, woL, bo, y);
}

// Round 6
// 399.058 us; speedup vs baseline: 1.2356x; 1.0438x over previous
//
#include <hip/hip_runtime.h>
#include <math.h>

// Problem constants
// B=16, DIM=256, HW=64, G=8, DH=64, DPG=32, TP=8, N=1024 patches, NG=8192
//
// Workspace layout:
//   shorts [0, 33554432)      qattB: bf16 q then att (in place), [n][pos][c]
//                             c = g*64+d, row stride 512. 64 MiB.
//   floats [16777216, +65536) vn: normalized sample grid, [ng][s][{x,y}]
//   shorts after that         woH/woL: wo split into bf16 hi/lo, [o][c]
//   shorts after that         wqH/wqL: wq split into bf16 hi/lo, [g][o][c]
// d_out (64 MB) doubles as the LN/patchify buffer xn, layout [n][pos][c]
// (pos-major! changed R6 for coalescing; k1 writes 256B/thread, k2 B-loads
// 2x float4/lane, k3 grid-sample 128B/wave per sample point).
//
// NOTE (R2-R4 post-mortems): the att-path numerics are on a knife's edge —
// the harness's second gate sits ~1 bf16-ulp above this kernel's exact
// output (R1/R5 pass at absmax = 2^-9 exactly). Changes that perturb att
// numerics all FAILED: v_cvt_pk_bf16_f32 (8.8e-3), f32-q sim in fused k23
// (2.44e-3), f16 att+wo (7.2e-3). ONLY bit-exact transforms allowed:
// this round = address remaps only (xn transpose, k4 block remap); every
// FP operation and its order is unchanged from the R5 pass.

#define WS_VN  16777216
#define WS_WOT 16842752

typedef __attribute__((ext_vector_type(8))) short short8;  // 8 bf16 (4 VGPRs)
typedef __attribute__((ext_vector_type(4))) short short4b; // 4 bf16 (8B store)
typedef __attribute__((ext_vector_type(4))) float f32x4;   // MFMA C/D frag

__device__ __forceinline__ short f2bf(float f) {           // RNE f32->bf16
  unsigned u = __builtin_bit_cast(unsigned, f);
  u += 0x7fff + ((u >> 16) & 1);
  return (short)(u >> 16);
}
__device__ __forceinline__ float bf2f(short h) {
  return __builtin_bit_cast(float, ((unsigned)(unsigned short)h) << 16);
}

// ---------------- K1: LayerNorm over channels + patchify (single-pass) -------
// xn layout [n][pos][c]: each thread owns (n,pos) and writes its 64-channel
// quarter as 256 B contiguous (16x float4). Arithmetic identical to R5.
__global__ __launch_bounds__(256) void k1_ln(const float* __restrict__ x,
    const float* __restrict__ ln_g, const float* __restrict__ ln_b,
    float* __restrict__ xn) {
  int blk = blockIdx.x;
  int b = blk >> 6, h = blk & 63;
  int t = threadIdx.x;
  int quarter = t >> 6, wcol = t & 63;
  const float* xrow = x + (size_t)b * (256 * 4096) + h * 64 + wcol;
  float vv[64];                               // hold 64 channels in regs
  float s = 0.f, ss = 0.f;
#pragma unroll
  for (int i = 0; i < 64; ++i) {
    float v = xrow[(size_t)(quarter * 64 + i) * 4096];
    vv[i] = v; s += v; ss += v * v;
  }
  __shared__ float sm[4][64], sq[4][64], mu_s[64], rs_s[64];
  sm[quarter][wcol] = s; sq[quarter][wcol] = ss;
  __syncthreads();
  if (t < 64) {
    float S  = sm[0][t] + sm[1][t] + sm[2][t] + sm[3][t];
    float SS = sq[0][t] + sq[1][t] + sq[2][t] + sq[3][t];
    float mu = S * (1.f / 256.f);
    float var = SS * (1.f / 256.f) - mu * mu;
    mu_s[t] = mu;
    rs_s[t] = 1.f / sqrtf(var + 1e-6f);
  }
  __syncthreads();
  float mu = mu_s[wcol], rs = rs_s[wcol];
  int it = h >> 3, p = h & 7, jt = wcol >> 3, qq = wcol & 7;
  int n = (it * 8 + jt) * 16 + b;             // patch id
  int pos = p * 8 + qq;
  float* xo = xn + (size_t)n * 16384 + pos * 256 + quarter * 64;
#pragma unroll
  for (int i = 0; i < 64; i += 4) {
    float4 o4;
    o4.x = (vv[i + 0] - mu) * rs * ln_g[quarter * 64 + i + 0] + ln_b[quarter * 64 + i + 0];
    o4.y = (vv[i + 1] - mu) * rs * ln_g[quarter * 64 + i + 1] + ln_b[quarter * 64 + i + 1];
    o4.z = (vv[i + 2] - mu) * rs * ln_g[quarter * 64 + i + 2] + ln_b[quarter * 64 + i + 2];
    o4.w = (vv[i + 3] - mu) * rs * ln_g[quarter * 64 + i + 3] + ln_b[quarter * 64 + i + 3];
    *(float4*)&xo[i] = o4;
  }
}

// ---- K0: merged weight prep — wo (131072) + wq (16384) bf16 hi/lo splits ----
__global__ __launch_bounds__(256) void k0_cvt(const float* __restrict__ wo,
    short* __restrict__ woH, short* __restrict__ woL,
    const float* __restrict__ wq,
    short* __restrict__ wqH, short* __restrict__ wqL) {
  int blk = blockIdx.x;
  if (blk < 512) {                            // wo path: 512*256 = 131072
    int idx = blk * 256 + threadIdx.x;
    float v = wo[idx];
    short hi = f2bf(v);
    woH[idx] = hi;
    woL[idx] = f2bf(v - bf2f(hi));
  } else {                                    // wq path: 64*256 = 16384
    int idx = (blk - 512) * 256 + threadIdx.x;
    float v = wq[idx];
    short hi = f2bf(v);
    wqH[idx] = hi;
    wqL[idx] = f2bf(v - bf2f(hi));
  }
}

// ---------------- K2: grouped q-projection (MFMA) + offset net ----------------
// 2048 blocks x 256 threads (4 waves). Block = (n, half-of-groups); the 4
// groups are processed sequentially against one shared qs transpose buffer.
// B-fragments now load as 2x float4 from the pos-major xn (was 8 scalar
// stride-256B loads). Values and all FP ops identical to R5.
__global__ __launch_bounds__(256, 4) void k2_qoff(const float* __restrict__ xn,
    const short* __restrict__ wqH, const short* __restrict__ wqL,
    const float* __restrict__ w1, const float* __restrict__ b1,
    const float* __restrict__ w2, short* __restrict__ qb,
    float* __restrict__ vn) {
  int blk = blockIdx.x;
  int n = blk >> 1, gh = blk & 1;
  int w = threadIdx.x >> 6;
  int lane = threadIdx.x & 63;
  int l15 = lane & 15, q4 = lane >> 4;
  __shared__ float qs[64][65];               // [channel][pos], bank-free reads

  const float* w1c = w1 + lane * 36;         // depthwise conv row (lane=channel)
  float b1v = b1[lane];
  float w2a = w2[lane];                      // oc=0 (x offset)
  float w2b = w2[64 + lane];                 // oc=1 (y offset)
  int oy = w >> 1, ox = w & 1;               // conv output = s = w
  int posc = w * 16 + l15;                   // this lane's output column

  for (int gi = 0; gi < 4; ++gi) {
    int g = gh * 4 + gi;
    int ng = n * 8 + g;
    // ---- B fragments: X[c][pos] hi/lo, c = g*32 + q4*8+j, pos = posc ----
    const float* xb = xn + (size_t)n * 16384 + posc * 256 + g * 32 + q4 * 8;
    float4 v0 = *(const float4*)xb;
    float4 v1 = *(const float4*)(xb + 4);
    float vj[8] = {v0.x, v0.y, v0.z, v0.w, v1.x, v1.y, v1.z, v1.w};
    short8 BH, BL;
#pragma unroll
    for (int j = 0; j < 8; ++j) {
      float v = vj[j];
      short hi = f2bf(v);
      BH[j] = hi;
      BL[j] = f2bf(v - bf2f(hi));
    }
    // ---- q tiles: A = wq[g] hi/lo, D[row=o][col=pos] ----
    const short* wqHg = wqH + g * 2048;
    const short* wqLg = wqL + g * 2048;
    short* qrow = qb + ((size_t)(n * 64 + posc) * 512 + g * 64);
#pragma unroll
    for (int mt = 0; mt < 4; ++mt) {
      short8 AH = *(const short8*)&wqHg[(mt * 16 + l15) * 32 + q4 * 8];
      short8 AL = *(const short8*)&wqLg[(mt * 16 + l15) * 32 + q4 * 8];
      f32x4 acc = {0.f, 0.f, 0.f, 0.f};
      acc = __builtin_amdgcn_mfma_f32_16x16x32_bf16(AH, BH, acc, 0, 0, 0);
      acc = __builtin_amdgcn_mfma_f32_16x16x32_bf16(AL, BH, acc, 0, 0, 0);
      acc = __builtin_amdgcn_mfma_f32_16x16x32_bf16(AH, BL, acc, 0, 0, 0);
      int obase = mt * 16 + q4 * 4;
#pragma unroll
      for (int reg = 0; reg < 4; ++reg) qs[obase + reg][posc] = acc[reg];
      short4b qv;
#pragma unroll
      for (int reg = 0; reg < 4; ++reg) qv[reg] = f2bf(acc[reg]);
      *(short4b*)&qrow[obase] = qv;          // 8B store, [pos][c] layout
    }
    __syncthreads();
    // ---- depthwise conv k=6 s=4 p=1: one output (c=lane, s=w) per thread ----
    float a = 0.f;
#pragma unroll
    for (int ky = 0; ky < 6; ++ky) {
      int iy = oy * 4 - 1 + ky;
      if (iy < 0 || iy > 7) continue;        // wave-uniform branch
#pragma unroll
      for (int kx = 0; kx < 6; ++kx) {
        int ix = ox * 4 - 1 + kx;
        if (ix < 0 || ix > 7) continue;
        a += w1c[ky * 6 + kx] * qs[lane][iy * 8 + ix];
      }
    }
    a += b1v;
    a = 0.5f * a * (1.f + erff(a * 0.70710678118654752f));   // exact GELU
    // ---- off2: out[oc][s] = sum_c w2[oc][c]*a  (butterfly over 64 lanes) ----
    float p0 = w2a * a, p1 = w2b * a;
#pragma unroll
    for (int st = 1; st < 64; st <<= 1) {
      p0 += __shfl_xor(p0, st, 64);
      p1 += __shfl_xor(p1, st, 64);
    }
    if (lane == 0) {
      float offx = tanhf(p0) * 4.f;
      float offy = tanhf(p1) * 4.f;
      float2 o2;
      o2.x = 2.f * ((float)ox + offx) - 1.f;
      o2.y = 2.f * ((float)oy + offy) - 1.f;
      *(float2*)&vn[(size_t)ng * 8 + w * 2] = o2;
    }
    __syncthreads();                          // qs reused by next group
  }
}

// ------------- K3: grid-sample + k/v proj + attention + CPB(MFMA) -------------
// 4 waves per block, one (n,g) per wave. q/att in bf16 [n][pos][c].
// Grid-sample reads now 128B wave-coalesced (pos-major xn, lanes span c).
__global__ __launch_bounds__(256, 3) void k3_attn(const float* __restrict__ xn,
    const float* __restrict__ wk, const float* __restrict__ wv,
    const float* __restrict__ vn,
    const float* __restrict__ cw1, const float* __restrict__ cb1,
    const float* __restrict__ cw2, const float* __restrict__ cb2,
    const float* __restrict__ cw3, const float* __restrict__ cb3,
    short* __restrict__ qattB) {
  int w = threadIdx.x >> 6;
  int lane = threadIdx.x & 63;
  int ng = blockIdx.x * 4 + w;
  int n = ng >> 3, g = ng & 7;
  __shared__ alignas(16) float kvs[4][32][4];
  __shared__ alignas(16) float ks[4][64][4];
  __shared__ alignas(16) float vs[4][64][4];
  __shared__ alignas(16) short bfragLDS[512 * 8];  // cw2 B-fragments, 8 KB
  __shared__ float biasS[4][4][64];                // CPB bias per (wave,s,pos)

  // --- block-cooperative: cw2 -> bf16 B-fragments in LDS ---
  {
    int t = threadIdx.x;
#pragma unroll
    for (int rep = 0; rep < 2; ++rep) {
      int slot = t + rep * 256;
      int combo = slot >> 6, ln = slot & 63;
      int kstep = combo >> 2, nt = combo & 3;
      int kbase = kstep * 32 + (ln >> 4) * 8;
      int ncol = nt * 16 + (ln & 15);
      short8 v;
#pragma unroll
      for (int jj = 0; jj < 8; ++jj) v[jj] = f2bf(cw2[(kbase + jj) * 64 + ncol]);
      *(short8*)&bfragLDS[slot * 8] = v;
    }
  }

  const float* vp = vn + (size_t)ng * 8;
  float vx0 = vp[0], vy0 = vp[1], vx1 = vp[2], vy1 = vp[3];
  float vx2 = vp[4], vy2 = vp[5], vx3 = vp[6], vy3 = vp[7];
  // --- bilinear grid-sample (xn pos-major: lanes span c -> coalesced) ---
  {
    int c = lane & 31, s2 = lane >> 5;
    const float* tile = xn + (size_t)n * 16384 + g * 32 + c;
#pragma unroll
    for (int rep = 0; rep < 2; ++rep) {
      int s = s2 + 2 * rep;
      float vxs = (rep == 0) ? (s2 ? vx1 : vx0) : (s2 ? vx3 : vx2);
      float vys = (rep == 0) ? (s2 ? vy1 : vy0) : (s2 ? vy3 : vy2);
      float X = 4.f * vxs + 3.5f, Y = 4.f * vys + 3.5f;
      float x0f = floorf(X), y0f = floorf(Y);
      int x0 = (int)x0f, y0 = (int)y0f;
      float wx1 = X - x0f, wy1 = Y - y0f;
      float acc = 0.f;
      for (int dy = 0; dy < 2; ++dy) {
        int iy = y0 + dy;
        if (iy < 0 || iy > 7) continue;
        float wyv = dy ? wy1 : 1.f - wy1;
        for (int dx = 0; dx < 2; ++dx) {
          int ix = x0 + dx;
          if (ix < 0 || ix > 7) continue;
          float wxv = dx ? wx1 : 1.f - wx1;
          acc += tile[(iy * 8 + ix) * 256] * wxv * wyv;
        }
      }
      kvs[w][c][s] = acc;
    }
  }
  __syncthreads();
  // --- k, v projection: lane = d ---
  {
    int d = lane;
    float ka0 = 0, ka1 = 0, ka2 = 0, ka3 = 0, va0 = 0, va1 = 0, va2 = 0, va3 = 0;
    const float4* wk4 = (const float4*)(wk + g * 2048 + d * 32);
    const float4* wv4 = (const float4*)(wv + g * 2048 + d * 32);
#pragma unroll
    for (int c4 = 0; c4 < 8; ++c4) {
      float4 a4 = wk4[c4], b4 = wv4[c4];
      float aw[4] = {a4.x, a4.y, a4.z, a4.w};
      float bw[4] = {b4.x, b4.y, b4.z, b4.w};
#pragma unroll
      for (int u = 0; u < 4; ++u) {
        float4 kv4 = *(const float4*)kvs[w][c4 * 4 + u];
        ka0 += aw[u] * kv4.x; ka1 += aw[u] * kv4.y;
        ka2 += aw[u] * kv4.z; ka3 += aw[u] * kv4.w;
        va0 += bw[u] * kv4.x; va1 += bw[u] * kv4.y;
        va2 += bw[u] * kv4.z; va3 += bw[u] * kv4.w;
      }
    }
    ks[w][d][0] = ka0; ks[w][d][1] = ka1; ks[w][d][2] = ka2; ks[w][d][3] = ka3;
    vs[w][d][0] = va0; vs[w][d][1] = va1; vs[w][d][2] = va2; vs[w][d][3] = va3;
  }
  __syncthreads();
  // --- sim = scale * q . k  (q bf16, vectorized 16B loads) ---
  float sim0 = 0, sim1 = 0, sim2 = 0, sim3 = 0;
  short* qrow = qattB + ((size_t)(n * 64 + lane) * 512 + g * 64);
#pragma unroll 2
  for (int d8 = 0; d8 < 8; ++d8) {
    short8 q8 = *(const short8*)&qrow[d8 * 8];
#pragma unroll
    for (int j = 0; j < 8; ++j) {
      float qv = bf2f(q8[j]);
      float4 k4 = *(const float4*)ks[w][d8 * 8 + j];
      sim0 += qv * k4.x; sim1 += qv * k4.y; sim2 += qv * k4.z; sim3 += qv * k4.w;
    }
  }
  float logit0 = sim0 * 0.125f, logit1 = sim1 * 0.125f;
  float logit2 = sim2 * 0.125f, logit3 = sim3 * 0.125f;

  // --- CPB via MFMA ---
  short8 bf[2][4];
#pragma unroll
  for (int kstep = 0; kstep < 2; ++kstep)
#pragma unroll
    for (int nt = 0; nt < 4; ++nt)
      bf[kstep][nt] = *(const short8*)&bfragLDS[((kstep * 4 + nt) * 64 + lane) * 8];
  int kcol = (lane >> 4) * 8;
  float c1x[16], c1y[16], c1b[16];
#pragma unroll
  for (int ks2 = 0; ks2 < 2; ++ks2)
#pragma unroll
    for (int jj = 0; jj < 8; ++jj) {
      int i = ks2 * 32 + kcol + jj;
      c1x[ks2 * 8 + jj] = cw1[i];
      c1y[ks2 * 8 + jj] = cw1[64 + i];
      c1b[ks2 * 8 + jj] = cb1[i];
    }
  int jme = lane & 15;
  float w3v[4], b2v[4];
#pragma unroll
  for (int nt = 0; nt < 4; ++nt) {
    w3v[nt] = cw3[nt * 16 + jme];
    b2v[nt] = cb2[nt * 16 + jme];
  }
  float gqx = (float)(jme & 7) * (2.f / 7.f) - 1.f;   // invariant across mt4
  float yrow = (float)(jme >> 3);
#pragma unroll 1
  for (int s = 0; s < 4; ++s) {
    float vxs = (s == 0) ? vx0 : (s == 1) ? vx1 : (s == 2) ? vx2 : vx3;
    float vys = (s == 0) ? vy0 : (s == 1) ? vy1 : (s == 2) ? vy2 : vy3;
    float px = gqx - vxs;
    float tx = copysignf(log1pf(fabsf(px)), px);
    float pre[16];
#pragma unroll
    for (int t2 = 0; t2 < 16; ++t2) pre[t2] = fmaf(tx, c1x[t2], c1b[t2]);
#pragma unroll 1
    for (int mt4 = 0; mt4 < 4; ++mt4) {
      float gqy = (float)(mt4 * 2) * (2.f / 7.f) + yrow * (2.f / 7.f) - 1.f;
      float py = gqy - vys;
      float ty = copysignf(log1pf(fabsf(py)), py);
      short8 af[2];
#pragma unroll
      for (int ks2 = 0; ks2 < 2; ++ks2)
#pragma unroll
        for (int jj = 0; jj < 8; ++jj) {
          float h = fmaxf(fmaf(ty, c1y[ks2 * 8 + jj], pre[ks2 * 8 + jj]), 0.f);
          af[ks2][jj] = f2bf(h);
        }
      f32x4 a0 = {0,0,0,0}, a1 = {0,0,0,0}, a2 = {0,0,0,0}, a3 = {0,0,0,0};
      a0 = __builtin_amdgcn_mfma_f32_16x16x32_bf16(af[0], bf[0][0], a0, 0, 0, 0);
      a0 = __builtin_amdgcn_mfma_f32_16x16x32_bf16(af[1], bf[1][0], a0, 0, 0, 0);
      a1 = __builtin_amdgcn_mfma_f32_16x16x32_bf16(af[0], bf[0][1], a1, 0, 0, 0);
      a1 = __builtin_amdgcn_mfma_f32_16x16x32_bf16(af[1], bf[1][1], a1, 0, 0, 0);
      a2 = __builtin_amdgcn_mfma_f32_16x16x32_bf16(af[0], bf[0][2], a2, 0, 0, 0);
      a2 = __builtin_amdgcn_mfma_f32_16x16x32_bf16(af[1], bf[1][2], a2, 0, 0, 0);
      a3 = __builtin_amdgcn_mfma_f32_16x16x32_bf16(af[0], bf[0][3], a3, 0, 0, 0);
      a3 = __builtin_amdgcn_mfma_f32_16x16x32_bf16(af[1], bf[1][3], a3, 0, 0, 0);
      float part[4];
#pragma unroll
      for (int reg = 0; reg < 4; ++reg) {
        part[reg] = w3v[0] * fmaxf(a0[reg] + b2v[0], 0.f)
                  + w3v[1] * fmaxf(a1[reg] + b2v[1], 0.f)
                  + w3v[2] * fmaxf(a2[reg] + b2v[2], 0.f)
                  + w3v[3] * fmaxf(a3[reg] + b2v[3], 0.f);
      }
#pragma unroll
      for (int st = 1; st < 16; st <<= 1)
#pragma unroll
        for (int reg = 0; reg < 4; ++reg)
          part[reg] += __shfl_xor(part[reg], st, 64);
      if (jme == 0) {
        int posO = mt4 * 16 + (lane >> 4) * 4;
#pragma unroll
        for (int reg = 0; reg < 4; ++reg) biasS[w][s][posO + reg] = part[reg];
      }
    }
  }
  __syncthreads();
  float c3 = cb3[0];
  logit0 += biasS[w][0][lane] + c3;
  logit1 += biasS[w][1][lane] + c3;
  logit2 += biasS[w][2][lane] + c3;
  logit3 += biasS[w][3][lane] + c3;
  float m = fmaxf(fmaxf(logit0, logit1), fmaxf(logit2, logit3));
  float e0 = expf(logit0 - m), e1 = expf(logit1 - m);
  float e2 = expf(logit2 - m), e3 = expf(logit3 - m);
  float inv = 1.f / (e0 + e1 + e2 + e3);
  e0 *= inv; e1 *= inv; e2 *= inv; e3 *= inv;
  // --- out = attn @ v, overwrite q row in place as bf16 ---
#pragma unroll 2
  for (int d8 = 0; d8 < 8; ++d8) {
    short8 o8;
#pragma unroll
    for (int j = 0; j < 8; ++j) {
      float4 v4 = *(const float4*)vs[w][d8 * 8 + j];
      o8[j] = f2bf(e0 * v4.x + e1 * v4.y + e2 * v4.z + e3 * v4.w);
    }
    *(short8*)&qrow[d8 * 8] = o8;
  }
}

// ---------------- K4: output projection via MFMA, no LDS ----------------
// Block remap (R6): block = (b, it, p) so the M-dim spans w=0..63 across the
// 8 jt-patches of one y row-span -> float4 stores covering full 256B rows
// per o per wave (was 4B-granule scatter assembled from 8 blocks).
// Same (att row . wo col) dot products, same K / hi-lo order -> bit-exact.
__global__ __launch_bounds__(256) void k4_mfma(const short* __restrict__ attB,
    const short* __restrict__ woH, const short* __restrict__ woL,
    const float* __restrict__ bo, float* __restrict__ y) {
  int blk = blockIdx.x;                 // 1024 = 16 b x 8 it x 8 p
  int b = blk & 15, it = (blk >> 4) & 7, p = blk >> 7;
  int wv = threadIdx.x >> 6;
  int lane = threadIdx.x & 63;
  int mr = lane & 15, kq = (lane >> 4) * 8;
  f32x4 acc[4][4];
#pragma unroll
  for (int mt = 0; mt < 4; ++mt)
#pragma unroll
    for (int nt = 0; nt < 4; ++nt) acc[mt][nt] = (f32x4){0.f, 0.f, 0.f, 0.f};
  int ncol0 = wv * 64 + mr;
  // A-row base for each mt: M-index w0 = mt*16+mr -> patch jt=w0>>3, q=w0&7
  size_t arow[4];
#pragma unroll
  for (int mt = 0; mt < 4; ++mt) {
    int w0 = mt * 16 + mr;
    int jt = w0 >> 3, q = w0 & 7;
    arow[mt] = ((size_t)((it * 8 + jt) * 16 + b) * 64 + p * 8 + q) * 512;
  }
#pragma unroll 2
  for (int kst = 0; kst < 16; ++kst) {
    int k0 = kst * 32 + kq;
    short8 a[4];
#pragma unroll
    for (int mt = 0; mt < 4; ++mt)
      a[mt] = *(const short8*)&attB[arow[mt] + k0];
#pragma unroll
    for (int nt = 0; nt < 4; ++nt) {
      size_t off = (size_t)(ncol0 + nt * 16) * 512 + k0;
      short8 bhi = *(const short8*)&woH[off];
      short8 blo = *(const short8*)&woL[off];
#pragma unroll
      for (int mt = 0; mt < 4; ++mt) {
        acc[mt][nt] = __builtin_amdgcn_mfma_f32_16x16x32_bf16(a[mt], bhi, acc[mt][nt], 0, 0, 0);
        acc[mt][nt] = __builtin_amdgcn_mfma_f32_16x16x32_bf16(a[mt], blo, acc[mt][nt], 0, 0, 0);
      }
    }
  }
#pragma unroll
  for (int nt = 0; nt < 4; ++nt) {
    int o = wv * 64 + nt * 16 + mr;
    float bov = bo[o];
    size_t ybase = ((size_t)b * 256 + o) * 4096 + (it * 8 + p) * 64;
#pragma unroll
    for (int mt = 0; mt < 4; ++mt) {
      int w0 = mt * 16 + (lane >> 4) * 4;   // 4 consecutive w per lane
      float4 o4;
      o4.x = acc[mt][nt][0] + bov;
      o4.y = acc[mt][nt][1] + bov;
      o4.z = acc[mt][nt][2] + bov;
      o4.w = acc[mt][nt][3] + bov;
      *(float4*)&y[ybase + w0] = o4;
    }
  }
}

extern "C" void kernel_launch(void* const* d_in, const int* in_sizes, int n_in,
                              void* d_out, int out_size, void* d_ws, size_t ws_size,
                              hipStream_t stream) {
  (void)in_sizes; (void)n_in; (void)out_size; (void)ws_size;
  const float* x    = (const float*)d_in[0];
  const float* ln_g = (const float*)d_in[1];
  const float* ln_b = (const float*)d_in[2];
  const float* wq   = (const float*)d_in[3];
  const float* wk   = (const float*)d_in[4];
  const float* wv   = (const float*)d_in[5];
  const float* ow1  = (const float*)d_in[6];
  const float* ob1  = (const float*)d_in[7];
  const float* ow2  = (const float*)d_in[8];
  const float* cw1  = (const float*)d_in[9];
  const float* cb1  = (const float*)d_in[10];
  const float* cw2  = (const float*)d_in[11];
  const float* cb2  = (const float*)d_in[12];
  const float* cw3  = (const float*)d_in[13];
  const float* cb3  = (const float*)d_in[14];
  const float* wo   = (const float*)d_in[15];
  const float* bo   = (const float*)d_in[16];
  float* y  = (float*)d_out;
  float* ws = (float*)d_ws;
  short* qattB = (short*)ws;               // 33,554,432 bf16 (q then att)
  float* vnb   = ws + WS_VN;               // 65,536 floats
  short* woH   = (short*)(ws + WS_WOT);    // 131072 shorts
  short* woL   = woH + 131072;             // 131072 shorts
  short* wqH   = woL + 131072;             // 16384 shorts
  short* wqL   = wqH + 16384;              // 16384 shorts
  float* xn = y;                           // reuse d_out as LN/patchify scratch

  k0_cvt<<<576, 256, 0, stream>>>(wo, woH, woL, wq, wqH, wqL);
  k1_ln<<<1024, 256, 0, stream>>>(x, ln_g, ln_b, xn);
  k2_qoff<<<2048, 256, 0, stream>>>(xn, wqH, wqL, ow1, ob1, ow2, qattB, vnb);
  k3_attn<<<2048, 256, 0, stream>>>(xn, wk, wv, vnb, cw1, cb1, cw2, cb2,
                                    cw3, cb3, qattB);
  k4_mfma<<<1024, 256, 0, stream>>>(qattB, woH, woL, bo, y);
}